// Round 9
// baseline (279.923 us; speedup 1.0000x reference)
//
#include <hip/hip_runtime.h>
#include <hip/hip_bf16.h>
#include <hip/hip_fp8.h>
#include <cmath>

// ---------------------------------------------------------------------------
// Round 9:
//   - linear2 fused into linear1 epilogue (EPI==3): per 128x128 tile the
//     K-loop already yields complete hrel values, so compute partial logits
//     sum(relu(v+lb1)*lW2) via shfl_xor over ml lanes + LDS-atomic cross-wave
//     combine; write per-y partial buffers (1.2 MB) instead of hrel (38 MB).
//     softmax_final sums 3 partials + lb2 -> logits + softmax. hrel deleted.
//   - Quad-gather aggregates: 4 edges per VMEM instruction (16-lane groups,
//     8 B/lane dwordx2), 2 shfl_xor reduction rounds (16, 32).
//   - (R8) compact bucketed CSR build; (R7) fp8 e4m3 xw; bf16 MFMA
//     128x128/BK32 GEMMs with global_load_lds w16 + XOR-swizzled LDS.
// ---------------------------------------------------------------------------

typedef __bf16 bf16;
typedef __bf16 bf16x2 __attribute__((ext_vector_type(2)));
typedef __bf16 bf16x4 __attribute__((ext_vector_type(4)));
typedef __bf16 bf16x8 __attribute__((ext_vector_type(8)));
typedef float  f32x4  __attribute__((ext_vector_type(4)));
typedef unsigned char fp8s;   // e4m3 storage byte

__device__ __forceinline__ void load_lds16(const bf16* g, bf16* l) {
    __builtin_amdgcn_global_load_lds(
        (const __attribute__((address_space(1))) void*)g,
        (__attribute__((address_space(3))) void*)l, 16, 0, 0);
}

__device__ __forceinline__ bf16 convert_out(float v, bf16*) { return (bf16)v; }
__device__ __forceinline__ fp8s convert_out(float v, fp8s*) {
    __hip_fp8_e4m3 q(v); return (fp8s)q.__x;
}

__device__ __forceinline__ float4 fp8x4_to_f4(unsigned int p) {
    __hip_fp8x2_e4m3 lo, hi;
    lo.__x = (__hip_fp8x2_storage_t)(p & 0xffffu);
    hi.__x = (__hip_fp8x2_storage_t)(p >> 16);
    float2 a = (float2)lo, c = (float2)hi;
    return make_float4(a.x, a.y, c.x, c.y);
}

// ---------------- CSR build (bucketed, N <= 65536 path) ----------------

__launch_bounds__(256)
__global__ void bucket_hist(const int* __restrict__ dst, int* __restrict__ bcnt, int e) {
    __shared__ int h[256];
    int t = threadIdx.x;
    h[t] = 0;
    __syncthreads();
    for (int i = blockIdx.x * 256 + t; i < e; i += gridDim.x * 256)
        atomicAdd(&h[dst[i] >> 8], 1);
    __syncthreads();
    if (h[t]) atomicAdd(&bcnt[t], h[t]);
}

__launch_bounds__(256)
__global__ void scan_tails(const int* __restrict__ bcnt, int* __restrict__ tailA,
                           int* __restrict__ bbase, int nbuck, int etot) {
    __shared__ int s[256];
    int t = threadIdx.x;
    int v = (t < nbuck) ? bcnt[t] : 0;
    s[t] = v;
    __syncthreads();
#pragma unroll
    for (int off = 1; off < 256; off <<= 1) {
        int tmp = (t >= off) ? s[t - off] : 0;
        __syncthreads();
        s[t] += tmp;
        __syncthreads();
    }
    int excl = s[t] - v;
    if (t < nbuck) { tailA[t] = excl; bbase[t] = excl; }
    if (t == 0) bbase[nbuck] = etot;
}

__launch_bounds__(256)
__global__ void bin_pairs(const int* __restrict__ src, const int* __restrict__ dst,
                          int* __restrict__ tail, unsigned int* __restrict__ pairs,
                          int e, int nbuck) {
    __shared__ int hist[256], base[256], cur[256];
    int t = threadIdx.x;
    hist[t] = 0; cur[t] = 0;
    __syncthreads();
    int perBlock = (e + gridDim.x - 1) / gridDim.x;
    int lo = blockIdx.x * perBlock;
    int hi = lo + perBlock; if (hi > e) hi = e;
    for (int i = lo + t; i < hi; i += 256)
        atomicAdd(&hist[dst[i] >> 8], 1);
    __syncthreads();
    if (t < nbuck && hist[t] > 0) base[t] = atomicAdd(&tail[t], hist[t]);
    __syncthreads();
    for (int i = lo + t; i < hi; i += 256) {
        int d = dst[i];
        int b = d >> 8;
        int r = atomicAdd(&cur[b], 1);
        pairs[base[b] + r] = (unsigned)src[i] | ((unsigned)(d & 255) << 16);
    }
}

#define FILL_CAP 6144
__launch_bounds__(256)
__global__ void csr_fill_full(const unsigned int* __restrict__ pairs,
                              const int* __restrict__ bbase,
                              int* __restrict__ rp, float* __restrict__ dinv,
                              int* __restrict__ col, int n, int etot) {
    __shared__ int cnt[256];
    __shared__ int ofs[256];
    __shared__ int ss[256];
    __shared__ int win[FILL_CAP];
    int b = blockIdx.x, t = threadIdx.x;
    int nodeBase = b << 8;
    int lo = bbase[b];
    int bcountE = bbase[b + 1] - lo;
    cnt[t] = 0;
    __syncthreads();
    for (int i = t; i < bcountE; i += 256)
        atomicAdd(&cnt[pairs[lo + i] >> 16], 1);
    __syncthreads();
    int myc = cnt[t];
    ss[t] = myc;
    __syncthreads();
#pragma unroll
    for (int off = 1; off < 256; off <<= 1) {
        int tmp = (t >= off) ? ss[t - off] : 0;
        __syncthreads();
        ss[t] += tmp;
        __syncthreads();
    }
    int excl = ss[t] - myc;
    ofs[t] = excl;
    int node = nodeBase + t;
    if (node < n) {
        rp[node]   = lo + excl;
        dinv[node] = rsqrtf((float)(myc + 1));    // +1 self-loop
        if (node == n - 1) rp[n] = etot;
    }
    cnt[t] = 0;
    __syncthreads();
    if (bcountE <= FILL_CAP) {
        for (int i = t; i < bcountE; i += 256) {
            unsigned p = pairs[lo + i];
            int dl = (int)(p >> 16);
            int r = atomicAdd(&cnt[dl], 1);
            win[ofs[dl] + r] = (int)(p & 0xffffu);
        }
        __syncthreads();
        for (int i = t; i < bcountE; i += 256) col[lo + i] = win[i];
    } else {
        for (int i = t; i < bcountE; i += 256) {
            unsigned p = pairs[lo + i];
            int dl = (int)(p >> 16);
            int r = atomicAdd(&cnt[dl], 1);
            col[lo + ofs[dl] + r] = (int)(p & 0xffffu);
        }
    }
}

// -------- fallback CSR build for N > 65536 (not used at this size) --------

__launch_bounds__(256)
__global__ void init_kernel(int* __restrict__ cnt, int* __restrict__ fill, int n) {
    int i = blockIdx.x * 256 + threadIdx.x;
    if (i < n) { cnt[i] = 1; fill[i] = 0; }
}

__launch_bounds__(256)
__global__ void hist_kernel(const int* __restrict__ dst, int* __restrict__ cnt, int e) {
    int i = blockIdx.x * 256 + threadIdx.x;
    if (i < e) atomicAdd(&cnt[dst[i]], 1);
}

__launch_bounds__(256)
__global__ void block_reduce(const int* __restrict__ cnt, int* __restrict__ bsum, int n) {
    __shared__ int s[256];
    int t = threadIdx.x;
    int i = blockIdx.x * 256 + t;
    int v = (i < n) ? cnt[i] - 1 : 0;
    s[t] = v;
    __syncthreads();
#pragma unroll
    for (int off = 128; off > 0; off >>= 1) {
        if (t < off) s[t] += s[t + off];
        __syncthreads();
    }
    if (t == 0) bsum[blockIdx.x] = s[0];
}

__launch_bounds__(256)
__global__ void scan_bsums(int* __restrict__ bsum, int nb) {
    __shared__ int s[256];
    int t = threadIdx.x;
    int v = (t < nb) ? bsum[t] : 0;
    s[t] = v;
    __syncthreads();
#pragma unroll
    for (int off = 1; off < 256; off <<= 1) {
        int tmp = (t >= off) ? s[t - off] : 0;
        __syncthreads();
        s[t] += tmp;
        __syncthreads();
    }
    if (t < nb) bsum[t] = s[t] - v;
}

__launch_bounds__(256)
__global__ void write_rp(const int* __restrict__ cnt, const int* __restrict__ bsum,
                         int* __restrict__ rp, float* __restrict__ dinv, int n, int etot) {
    __shared__ int s[256];
    int t = threadIdx.x;
    int i = blockIdx.x * 256 + t;
    int c = (i < n) ? cnt[i] : 1;
    int v = c - 1;
    s[t] = v;
    __syncthreads();
#pragma unroll
    for (int off = 1; off < 256; off <<= 1) {
        int tmp = (t >= off) ? s[t - off] : 0;
        __syncthreads();
        s[t] += tmp;
        __syncthreads();
    }
    if (i < n) {
        rp[i]   = bsum[blockIdx.x] + s[t] - v;
        dinv[i] = rsqrtf((float)c);
        if (i == n - 1) rp[n] = etot;
    }
}

__launch_bounds__(256)
__global__ void fill_kernel(const int* __restrict__ src, const int* __restrict__ dst,
                            const int* __restrict__ rp, int* __restrict__ fill,
                            int* __restrict__ col, int e) {
    int i = blockIdx.x * 256 + threadIdx.x;
    if (i < e) {
        int d = dst[i];
        int pos = rp[d] + atomicAdd(&fill[d], 1);
        col[pos] = src[i];
    }
}

// ---------------- prep (fused) ----------------
__launch_bounds__(256)
__global__ void prep_all(const float* __restrict__ W1, const float* __restrict__ W2,
                         const float* __restrict__ W3, const float* __restrict__ lW1,
                         const float* __restrict__ x, const float* __restrict__ dinv,
                         bf16* __restrict__ Wt1, bf16* __restrict__ Wt2,
                         bf16* __restrict__ Wt3, bf16* __restrict__ lW1_bf,
                         bf16* __restrict__ xs0, int n64) {
    int i = blockIdx.x * 256 + threadIdx.x;
    if (i < 8192) {
        int k = i >> 7, c = i & 127; Wt1[c * 64 + k] = (bf16)W1[i];
    } else if (i < 24576) {
        int j = i - 8192; int k = j >> 7, c = j & 127; Wt2[c * 128 + k] = (bf16)W2[j];
    } else if (i < 40960) {
        int j = i - 24576; int k = j >> 7, c = j & 127; Wt3[c * 128 + k] = (bf16)W3[j];
    } else if (i < 188416) {
        int j = i - 40960; lW1_bf[j] = (bf16)lW1[j];
    } else {
        int j = i - 188416;
        if (j < n64) xs0[j] = (bf16)(x[j] * dinv[j >> 6]);
    }
}

// ---------------- MFMA GEMM ----------------
// EPI: 0 = rowScale only, 1 = +bias, 2 = +bias+ReLU (store OutT),
//      3 = LOGITS: partial logits of relu(v+bias) @ lW2^T -> part (no C store)
template<int EPI, typename OutT>
__launch_bounds__(256, 4)
__global__ void mfma_gemm(const bf16* __restrict__ A, int strideA, int K,
                          const bf16* __restrict__ Bt,
                          const float* __restrict__ bias,
                          const float* __restrict__ rowScale,
                          OutT* __restrict__ C, int strideC, int n,
                          const float* __restrict__ lW2 = nullptr,
                          float* __restrict__ part = nullptr) {
    __shared__ bf16 As[128 * 32];
    __shared__ bf16 Bs[128 * 32];
    __shared__ float plds[128 * 2];   // only used by EPI==3
    int t = threadIdx.x;
    int rowBase = blockIdx.x * 128;
    int colBase = blockIdx.y * 128;

    int lane = t & 63;
    int wv   = t >> 6;
    int wr   = wv >> 1, wc = wv & 1;
    int ml   = lane & 15, quad = lane >> 4;

    if (EPI == 3) { plds[t] = 0.f; if (t < 256) {} }

    f32x4 acc[4][4];
#pragma unroll
    for (int i = 0; i < 4; ++i)
#pragma unroll
        for (int j = 0; j < 4; ++j) acc[i][j] = (f32x4){0.f, 0.f, 0.f, 0.f};

    int srow0 = wv * 32 + (lane >> 2);
    int cchunk = lane & 3;

    for (int kt = 0; kt < K; kt += 32) {
        __syncthreads();
#pragma unroll
        for (int inst = 0; inst < 2; ++inst) {
            int r  = srow0 + inst * 16;
            int gc = (cchunk ^ (r & 3)) * 8;
            int gr = rowBase + r; if (gr >= n) gr = n - 1;
            load_lds16(A + (size_t)gr * strideA + kt + gc,
                       &As[(wv * 128 + inst * 64) * 8]);
            int br = colBase + r;
            load_lds16(Bt + (size_t)br * K + kt + gc,
                       &Bs[(wv * 128 + inst * 64) * 8]);
        }
        __syncthreads();
        bf16x8 af[4], bfv[4];
#pragma unroll
        for (int i = 0; i < 4; ++i) {
            int ra = wr * 64 + i * 16 + ml;
            int rb = wc * 64 + i * 16 + ml;
            af[i]  = *(const bf16x8*)&As[(ra * 4 + (quad ^ (ra & 3))) * 8];
            bfv[i] = *(const bf16x8*)&Bs[(rb * 4 + (quad ^ (rb & 3))) * 8];
        }
#pragma unroll
        for (int i = 0; i < 4; ++i)
#pragma unroll
            for (int j = 0; j < 4; ++j)
                acc[i][j] = __builtin_amdgcn_mfma_f32_16x16x32_bf16(
                    af[i], bfv[j], acc[i][j], 0, 0, 0);
    }

    if (EPI == 3) {
        // logits epilogue: no C store. Per-lane cols gc_j = colBase+wc*64+j*16+ml.
        float b4[4], w0[4], w1[4];
#pragma unroll
        for (int j = 0; j < 4; ++j) {
            int gc = colBase + wc * 64 + j * 16 + ml;
            b4[j] = bias[gc];
            w0[j] = lW2[gc];
            w1[j] = lW2[384 + gc];
        }
#pragma unroll
        for (int i = 0; i < 4; ++i) {
#pragma unroll
            for (int reg = 0; reg < 4; ++reg) {
                float p0 = 0.f, p1 = 0.f;
#pragma unroll
                for (int j = 0; j < 4; ++j) {
                    float v = fmaxf(acc[i][j][reg] + b4[j], 0.f);
                    p0 += v * w0[j];
                    p1 += v * w1[j];
                }
                // reduce over ml lanes (bits 0..3 of lane)
#pragma unroll
                for (int m = 1; m < 16; m <<= 1) {
                    p0 += __shfl_xor(p0, m, 64);
                    p1 += __shfl_xor(p1, m, 64);
                }
                if (ml == 0) {
                    int rl = wr * 64 + i * 16 + quad * 4 + reg;
                    atomicAdd(&plds[rl * 2 + 0], p0);
                    atomicAdd(&plds[rl * 2 + 1], p1);
                }
            }
        }
        __syncthreads();
        int r = t >> 1, c = t & 1;
        int gr = rowBase + r;
        if (gr < n)
            part[((size_t)blockIdx.y * n + gr) * 2 + c] = plds[t];
        return;
    }

#pragma unroll
    for (int i = 0; i < 4; ++i) {
#pragma unroll
        for (int reg = 0; reg < 4; ++reg) {
            int gr = rowBase + wr * 64 + i * 16 + quad * 4 + reg;
            if (gr < n) {
                float sc = (EPI == 0 && rowScale) ? rowScale[gr] : 1.f;
#pragma unroll
                for (int j = 0; j < 4; ++j) {
                    int gc = colBase + wc * 64 + j * 16 + ml;
                    float v = acc[i][j][reg];
                    if (EPI >= 1) v += bias[gc];
                    if (EPI == 2) v = fmaxf(v, 0.f);
                    C[(size_t)gr * strideC + gc] = convert_out(v * sc, (OutT*)nullptr);
                }
            }
        }
    }
}

// ---------------- aggregation (quad-gather) ----------------
// Wave = 1 node; four 16-lane groups each gather a DIFFERENT edge per VMEM
// instruction (8 B/lane x 64 = 512 B = 4 rows of 128 B). Edge ids via __shfl;
// groups combined with shfl_xor(16/32); self/bias/scale on g==0 lanes.

// 64-dim bf16 rows (128 B): lane s covers cols [s*4, +4).
__launch_bounds__(256)
__global__ void aggregate64(const bf16* __restrict__ xs, const int* __restrict__ rp,
                            const int* __restrict__ col, const float* __restrict__ dinv,
                            bf16* __restrict__ out, int n) {
    int gid  = blockIdx.x * 256 + threadIdx.x;
    int v    = gid >> 6;
    int lane = gid & 63;
    if (v >= n) return;
    int g = lane >> 4;       // group 0..3 (edge slot)
    int s = lane & 15;       // 16 lanes cover one 128-B row
    float di = dinv[v];
    int b = rp[v], e = rp[v + 1];
    int deg = e - b;
    const bf16* base = xs + s * 4;
    float a0 = 0.f, a1 = 0.f, a2 = 0.f, a3 = 0.f;
    for (int j0 = 0; j0 < deg; j0 += 64) {
        int rem = deg - j0; if (rem > 64) rem = 64;
        int cj = (lane < rem) ? col[b + j0 + lane] : 0;
        int jj = 0;
        for (; jj + 4 <= rem; jj += 4) {
            int eidx = __shfl(cj, jj + g, 64);
            bf16x4 m = *(const bf16x4*)(base + (size_t)eidx * 64);
            a0 += (float)m[0]; a1 += (float)m[1];
            a2 += (float)m[2]; a3 += (float)m[3];
        }
        if (jj < rem) {
            int idx = jj + g; if (idx >= rem) idx = jj;
            int eidx = __shfl(cj, idx, 64);
            if (jj + g < rem) {
                bf16x4 m = *(const bf16x4*)(base + (size_t)eidx * 64);
                a0 += (float)m[0]; a1 += (float)m[1];
                a2 += (float)m[2]; a3 += (float)m[3];
            }
        }
    }
#pragma unroll
    for (int m = 16; m < 64; m <<= 1) {
        a0 += __shfl_xor(a0, m, 64);
        a1 += __shfl_xor(a1, m, 64);
        a2 += __shfl_xor(a2, m, 64);
        a3 += __shfl_xor(a3, m, 64);
    }
    if (g == 0) {
        bf16x4 mv = *(const bf16x4*)(base + (size_t)v * 64);
        bf16x4 o;
        o[0] = (bf16)(di * (a0 + (float)mv[0]));
        o[1] = (bf16)(di * (a1 + (float)mv[1]));
        o[2] = (bf16)(di * (a2 + (float)mv[2]));
        o[3] = (bf16)(di * (a3 + (float)mv[3]));
        *(bf16x4*)(out + (size_t)v * 64 + s * 4) = o;
    }
}

// 128-dim fp8 rows (128 B): lane s covers cols [s*8, +8).
__launch_bounds__(256)
__global__ void aggregate_fp8(const fp8s* __restrict__ xs, const int* __restrict__ rp,
                              const int* __restrict__ col, const float* __restrict__ dinv,
                              const float* __restrict__ bias, bf16* __restrict__ out,
                              int outStride, int n) {
    int gid  = blockIdx.x * 256 + threadIdx.x;
    int v    = gid >> 6;
    int lane = gid & 63;
    if (v >= n) return;
    int g = lane >> 4;
    int s = lane & 15;
    float di = dinv[v];
    int b = rp[v], e = rp[v + 1];
    int deg = e - b;
    const fp8s* base = xs + s * 8;
    float a0 = 0.f, a1 = 0.f, a2 = 0.f, a3 = 0.f;
    float a4 = 0.f, a5 = 0.f, a6 = 0.f, a7 = 0.f;
    for (int j0 = 0; j0 < deg; j0 += 64) {
        int rem = deg - j0; if (rem > 64) rem = 64;
        int cj = (lane < rem) ? col[b + j0 + lane] : 0;
        int jj = 0;
        for (; jj + 4 <= rem; jj += 4) {
            int eidx = __shfl(cj, jj + g, 64);
            uint2 p = *(const uint2*)(base + (size_t)eidx * 128);
            float4 f0 = fp8x4_to_f4(p.x), f1 = fp8x4_to_f4(p.y);
            a0 += f0.x; a1 += f0.y; a2 += f0.z; a3 += f0.w;
            a4 += f1.x; a5 += f1.y; a6 += f1.z; a7 += f1.w;
        }
        if (jj < rem) {
            int idx = jj + g; if (idx >= rem) idx = jj;
            int eidx = __shfl(cj, idx, 64);
            if (jj + g < rem) {
                uint2 p = *(const uint2*)(base + (size_t)eidx * 128);
                float4 f0 = fp8x4_to_f4(p.x), f1 = fp8x4_to_f4(p.y);
                a0 += f0.x; a1 += f0.y; a2 += f0.z; a3 += f0.w;
                a4 += f1.x; a5 += f1.y; a6 += f1.z; a7 += f1.w;
            }
        }
    }
#pragma unroll
    for (int m = 16; m < 64; m <<= 1) {
        a0 += __shfl_xor(a0, m, 64); a1 += __shfl_xor(a1, m, 64);
        a2 += __shfl_xor(a2, m, 64); a3 += __shfl_xor(a3, m, 64);
        a4 += __shfl_xor(a4, m, 64); a5 += __shfl_xor(a5, m, 64);
        a6 += __shfl_xor(a6, m, 64); a7 += __shfl_xor(a7, m, 64);
    }
    if (g == 0) {
        uint2 pv = *(const uint2*)(base + (size_t)v * 128);
        float4 v0 = fp8x4_to_f4(pv.x), v1 = fp8x4_to_f4(pv.y);
        float4 bb0 = *(const float4*)(bias + s * 8);
        float4 bb1 = *(const float4*)(bias + s * 8 + 4);
        bf16x8 o;
        o[0] = (bf16)(di * (a0 + v0.x) + bb0.x);
        o[1] = (bf16)(di * (a1 + v0.y) + bb0.y);
        o[2] = (bf16)(di * (a2 + v0.z) + bb0.z);
        o[3] = (bf16)(di * (a3 + v0.w) + bb0.w);
        o[4] = (bf16)(di * (a4 + v1.x) + bb1.x);
        o[5] = (bf16)(di * (a5 + v1.y) + bb1.y);
        o[6] = (bf16)(di * (a6 + v1.z) + bb1.z);
        o[7] = (bf16)(di * (a7 + v1.w) + bb1.w);
        *(bf16x8*)(out + (size_t)v * outStride + s * 8) = o;
    }
}

// ---------------- softmax final ----------------
// logits = part[0]+part[1]+part[2]+lb2; out[0:2N)=logits, out[2N:4N)=softmax
__launch_bounds__(256)
__global__ void softmax_final(const float* __restrict__ part, const float* __restrict__ lb2,
                              float* __restrict__ out, int n) {
    int i = blockIdx.x * 256 + threadIdx.x;
    if (i >= n) return;
    size_t seg = (size_t)n * 2;
    float2 p0 = *(const float2*)(part + (size_t)i * 2);
    float2 p1 = *(const float2*)(part + seg + (size_t)i * 2);
    float2 p2 = *(const float2*)(part + 2 * seg + (size_t)i * 2);
    float l0 = p0.x + p1.x + p2.x + lb2[0];
    float l1 = p0.y + p1.y + p2.y + lb2[1];
    *(float2*)(out + (size_t)i * 2) = make_float2(l0, l1);
    float m  = fmaxf(l0, l1);
    float e0 = expf(l0 - m), e1 = expf(l1 - m);
    float inv = 1.f / (e0 + e1);
    *(float2*)(out + seg + (size_t)i * 2) = make_float2(e0 * inv, e1 * inv);
}

extern "C" void kernel_launch(void* const* d_in, const int* in_sizes, int n_in,
                              void* d_out, int out_size, void* d_ws, size_t ws_size,
                              hipStream_t stream) {
    const float* x   = (const float*)d_in[0];
    const int*   ei  = (const int*)d_in[1];
    const float* W1  = (const float*)d_in[2];
    const float* b1  = (const float*)d_in[3];
    const float* W2  = (const float*)d_in[4];
    const float* b2  = (const float*)d_in[5];
    const float* W3  = (const float*)d_in[6];
    const float* b3  = (const float*)d_in[7];
    const float* lW1 = (const float*)d_in[8];
    const float* lb1 = (const float*)d_in[9];
    const float* lW2 = (const float*)d_in[10];
    const float* lb2 = (const float*)d_in[11];
    float* out = (float*)d_out;

    int N = in_sizes[0] / 64;
    int E = in_sizes[1] / 2;
    const int* src = ei;
    const int* dst = ei + E;

    char* ws = (char*)d_ws;
    size_t off = 0;
    auto take = [&](size_t bytes) -> char* {
        char* p = ws + off;
        off += (bytes + 255) & ~(size_t)255;
        return p;
    };
    int nBlk  = (N + 255) / 256;
    int nbuck = nBlk;
    int*   cnt    = (int*)take((size_t)N * 4);         // fallback only
    int*   fill   = (int*)take((size_t)N * 4);         // fallback only
    int*   rp     = (int*)take((size_t)(N + 1) * 4);
    float* dinv   = (float*)take((size_t)N * 4);
    int*   bsum   = (int*)take((size_t)nBlk * 4);      // fallback only
    int*   bcnt   = (int*)take((size_t)nbuck * 4);
    int*   tailA  = (int*)take((size_t)nbuck * 4);
    int*   bbase  = (int*)take((size_t)(nbuck + 1) * 4);
    int*   col    = (int*)take((size_t)E * 4);
    unsigned int* pairs = (unsigned int*)take((size_t)E * 4);
    bf16*  xs0    = (bf16*)take((size_t)N * 64 * 2);
    bf16*  ax     = (bf16*)take((size_t)N * 64 * 2);
    bf16*  Wt1    = (bf16*)take((size_t)64 * 128 * 2);
    bf16*  Wt2    = (bf16*)take((size_t)128 * 128 * 2);
    bf16*  Wt3    = (bf16*)take((size_t)128 * 128 * 2);
    bf16*  lW1_bf = (bf16*)take((size_t)384 * 384 * 2);
    fp8s*  xw8    = (fp8s*)take((size_t)N * 128);
    bf16*  hcat   = (bf16*)take((size_t)N * 384 * 2);
    float* part   = (float*)take((size_t)N * 2 * 3 * 4);

    // CSR build
    if (nbuck <= 256 && N <= 65536) {
        hipMemsetAsync(bcnt, 0, (size_t)nbuck * 4, stream);
        bucket_hist<<<256, 256, 0, stream>>>(dst, bcnt, E);
        scan_tails<<<1, 256, 0, stream>>>(bcnt, tailA, bbase, nbuck, E);
        bin_pairs<<<nbuck, 256, 0, stream>>>(src, dst, tailA, pairs, E, nbuck);
        csr_fill_full<<<nbuck, 256, 0, stream>>>(pairs, bbase, rp, dinv, col, N, E);
    } else {
        init_kernel<<<nBlk, 256, 0, stream>>>(cnt, fill, N);
        hist_kernel<<<(E + 255) / 256, 256, 0, stream>>>(dst, cnt, E);
        block_reduce<<<nBlk, 256, 0, stream>>>(cnt, bsum, N);
        scan_bsums<<<1, 256, 0, stream>>>(bsum, nBlk);
        write_rp<<<nBlk, 256, 0, stream>>>(cnt, bsum, rp, dinv, N, E);
        fill_kernel<<<(E + 255) / 256, 256, 0, stream>>>(src, dst, rp, fill, col, E);
    }

    // prep (weights + dinv-scaled x cast, one launch)
    int prepElems = 188416 + N * 64;
    prep_all<<<(prepElems + 255) / 256, 256, 0, stream>>>(
        W1, W2, W3, lW1, x, dinv, Wt1, Wt2, Wt3, lW1_bf, xs0, N * 64);

    int gemmBlocks = (N + 127) / 128;
    int aggBlocks  = (N + 3) / 4;

    // conv1: aggregate first (64-dim bf16), then GEMM with bias epilogue
    aggregate64<<<aggBlocks, 256, 0, stream>>>(xs0, rp, col, dinv, ax, N);
    mfma_gemm<1, bf16><<<dim3(gemmBlocks, 1), 256, 0, stream>>>(
        ax, 64, 64, Wt1, b1, nullptr, hcat + 0, 384, N);
    // conv2: GEMM -> fp8 xw (rows pre-scaled by dinv), aggregate fp8 (+bias)
    mfma_gemm<0, fp8s><<<dim3(gemmBlocks, 1), 256, 0, stream>>>(
        hcat + 0, 384, 128, Wt2, nullptr, dinv, xw8, 128, N);
    aggregate_fp8<<<aggBlocks, 256, 0, stream>>>(xw8, rp, col, dinv, b2, hcat + 128, 384, N);
    // conv3
    mfma_gemm<0, fp8s><<<dim3(gemmBlocks, 1), 256, 0, stream>>>(
        hcat + 128, 384, 128, Wt3, nullptr, dinv, xw8, 128, N);
    aggregate_fp8<<<aggBlocks, 256, 0, stream>>>(xw8, rp, col, dinv, b3, hcat + 256, 384, N);

    // MLP head: linear1+relu+linear2 fused (partial logits per y), then softmax
    mfma_gemm<3, bf16><<<dim3(gemmBlocks, 3), 256, 0, stream>>>(
        hcat, 384, 384, lW1_bf, lb1, nullptr, (bf16*)nullptr, 0, N, lW2, part);
    softmax_final<<<(N + 255) / 256, 256, 0, stream>>>(part, lb2, out, N);
}